// Round 3
// baseline (128.469 us; speedup 1.0000x reference)
//
#include <hip/hip_runtime.h>
#include <hip/hip_bf16.h>

typedef __attribute__((ext_vector_type(8))) short short8;
typedef __attribute__((ext_vector_type(4))) float f32x4;

#define H_DIM 768
#define E_EXP 16
#define T_TASK 8
#define KSEL 4
#define L_SEQ 8192
#define B_BATCH 16
#define EW_STRIDE (768*768)

#define WCT_BLOCKS 576     // 24 x 24 tiles of 32x32
#define FILLA_BLOCKS 1472  // batches 1..8  (201.3 MB)
#define GEMM_BLOCKS 384    // 64 m-tiles x 6 n-tiles of 128x128
#define FILLB_BLOCKS 1472  // batches 9..15 (176.2 MB)
#define AS_LD 40           // padded A-row stride in LDS (breaks write conflicts)

// --------------------------------------------------------------- gating -----
// In-block gating: deterministic, recomputed per wct block (identical results).
__device__ __forceinline__ void gating_block(
    const float* __restrict__ task_full,
    const float* __restrict__ gate_w,
    const float* __restrict__ gate_b,
    float* silu_s, float (*logits)[E_EXP],
    float* g_sh, int* i_sh,
    float* __restrict__ out_tail, bool write_tail) {
  const int tid = threadIdx.x;
  for (int i = tid; i < T_TASK * H_DIM; i += 256) {
    float v = task_full[i];
    silu_s[i] = v / (1.f + expf(-v));
  }
  __syncthreads();
  if (tid < T_TASK * E_EXP) {
    const int t = tid >> 4, e = tid & 15;
    float a0 = 0.f, a1 = 0.f, a2 = 0.f, a3 = 0.f;
    const float* sl = &silu_s[t * H_DIM];
    for (int h = 0; h < H_DIM; h += 4) {
      a0 += sl[h]     * gate_w[(h)     * E_EXP + e];
      a1 += sl[h + 1] * gate_w[(h + 1) * E_EXP + e];
      a2 += sl[h + 2] * gate_w[(h + 2) * E_EXP + e];
      a3 += sl[h + 3] * gate_w[(h + 3) * E_EXP + e];
    }
    logits[t][e] = (a0 + a1) + (a2 + a3) + gate_b[e];
  }
  __syncthreads();
  if (tid < T_TASK) {
    const int t = tid;
    float p[E_EXP];
    float m = -1e30f;
    for (int e = 0; e < E_EXP; ++e) m = fmaxf(m, logits[t][e]);
    float s = 0.f;
    for (int e = 0; e < E_EXP; ++e) { p[e] = expf(logits[t][e] - m); s += p[e]; }
    const float inv = 1.f / s;
    for (int e = 0; e < E_EXP; ++e) p[e] *= inv;
    bool used[E_EXP];
    for (int e = 0; e < E_EXP; ++e) used[e] = false;
    float g[KSEL]; int sel[KSEL];
    for (int k = 0; k < KSEL; ++k) {
      float bv = -1.f; int bi = 0;
      for (int e = 0; e < E_EXP; ++e)
        if (!used[e] && p[e] > bv) { bv = p[e]; bi = e; }
      used[bi] = true; sel[k] = bi; g[k] = bv;
    }
    if (write_tail) {
      for (int e = 0; e < E_EXP; ++e)
        out_tail[E_EXP + t * E_EXP + e] = used[e] ? 1.f : 0.f;
      if (t == 0)
        for (int e = 0; e < E_EXP; ++e) out_tail[e] = p[e];
    }
    if (t == 0)
      for (int k = 0; k < KSEL; ++k) { g_sh[k] = g[k]; i_sh[k] = sel[k]; }
  }
  __syncthreads();
}

// ------------------------------------------------------------------ K_A -----
// blocks 0..575: inline gating + wct tile (wct[o][d] = sum_k g_k * W[idx_k][d][o])
// rest: fill batches 1..8 with 1.0
__global__ __launch_bounds__(256) void kA_wct_fill(
    const float* __restrict__ task_full,
    const float* __restrict__ gate_w,
    const float* __restrict__ gate_b,
    const float* __restrict__ expert_w,
    __hip_bfloat16* __restrict__ wct,
    float* __restrict__ out_tail,
    float4* __restrict__ fill_p, size_t fill_n4) {
  const int bid = blockIdx.x;
  const int tid = threadIdx.x;
  if (bid < WCT_BLOCKS) {
    __shared__ float silu_s[T_TASK * H_DIM];
    __shared__ float logits[T_TASK][E_EXP];
    __shared__ float g_sh[KSEL];
    __shared__ int   i_sh[KSEL];
    __shared__ float tile[32][33];
    gating_block(task_full, gate_w, gate_b, silu_s, logits, g_sh, i_sh,
                 out_tail, bid == 0);
    const float g0 = g_sh[0], g1 = g_sh[1], g2 = g_sh[2], g3 = g_sh[3];
    const size_t e0 = (size_t)i_sh[0] * EW_STRIDE;
    const size_t e1 = (size_t)i_sh[1] * EW_STRIDE;
    const size_t e2 = (size_t)i_sh[2] * EW_STRIDE;
    const size_t e3 = (size_t)i_sh[3] * EW_STRIDE;
    const int d0 = (bid % 24) * 32, o0 = (bid / 24) * 32;
    const int c = tid & 31;
    const int r0 = tid >> 5;  // 0..7
#pragma unroll
    for (int it = 0; it < 4; ++it) {
      const int rr = it * 8 + r0;  // d offset
      const size_t off = (size_t)(d0 + rr) * H_DIM + o0 + c;
      tile[rr][c] = g0 * expert_w[e0 + off] + g1 * expert_w[e1 + off] +
                    g2 * expert_w[e2 + off] + g3 * expert_w[e3 + off];
    }
    __syncthreads();
#pragma unroll
    for (int it = 0; it < 4; ++it) {
      const int rr = it * 8 + r0;  // o offset
      wct[(size_t)(o0 + rr) * H_DIM + d0 + c] = __float2bfloat16(tile[c][rr]);
    }
  } else {
    const int fb = bid - WCT_BLOCKS;
    size_t i = (size_t)fb * 256 + tid;
    const size_t stride = (size_t)FILLA_BLOCKS * 256;
    const float4 one = make_float4(1.f, 1.f, 1.f, 1.f);
    for (; i < fill_n4; i += stride) fill_p[i] = one;
  }
}

// ------------------------------------------------------------------ K_B -----
__device__ __forceinline__ void gload_lds16(const void* g, void* l) {
  __builtin_amdgcn_global_load_lds((const __attribute__((address_space(1))) void*)g,
                                   (__attribute__((address_space(3))) void*)l, 16, 0, 0);
}

// blocks < GEMM_BLOCKS: C[l][o] = 1 + sum_d X[l][d]*Bt[o][d] (X is f32, cvt in
// staging); rest: fill batches 9..15
__global__ __launch_bounds__(256) void kB_gemm_fill(
    const float* __restrict__ X,                  // x[0] f32 [8192][768]
    const __hip_bfloat16* __restrict__ Bt,        // wct [768][768]
    float* __restrict__ C,
    float4* __restrict__ fill_p, size_t fill_n4) {
  const int bid = blockIdx.x;
  const int tid = threadIdx.x;
  if (bid < GEMM_BLOCKS) {
    __shared__ __hip_bfloat16 As[128 * AS_LD];
    __shared__ __hip_bfloat16 Bs[128 * 32];
    const int m0 = (bid & 63) * 128;   // consecutive bids share n0 -> share Bt in L2
    const int n0 = (bid >> 6) * 128;
    const int lane = tid & 63;
    const int w = tid >> 6;
    const int wr = w >> 1, wc = w & 1;           // 2x2 wave grid, 64x64 each
    const int ra = tid >> 1, sa = tid & 1;       // A staging: row, 16-float seg
    const int rb = tid >> 2, sb = tid & 3;       // B staging: row, 16B seg
    const float* gx = X + (size_t)(m0 + ra) * H_DIM + sa * 16;
    const __hip_bfloat16* gb = Bt + (size_t)(n0 + rb) * H_DIM + sb * 8;
    f32x4 acc[4][4] = {};
    const int arow = wr * 64 + (lane & 15);
    const int brow = wc * 64 + (lane & 15);
    const int koff = (lane >> 4) * 8;  // same k mapping for A and B -> k-perm safe
    for (int k0 = 0; k0 < H_DIM; k0 += 32) {
      // B -> LDS (DMA)
      gload_lds16(gb + k0,              &Bs[tid * 8]);
      gload_lds16(gb + 64 * H_DIM + k0, &Bs[2048 + tid * 8]);
      // A: f32 load -> bf16 cvt -> LDS
      const float4 f0 = *(const float4*)(gx + k0);
      const float4 f1 = *(const float4*)(gx + k0 + 4);
      const float4 f2 = *(const float4*)(gx + k0 + 8);
      const float4 f3 = *(const float4*)(gx + k0 + 12);
      alignas(16) __hip_bfloat16 hb[16];
      hb[0]  = __float2bfloat16(f0.x); hb[1]  = __float2bfloat16(f0.y);
      hb[2]  = __float2bfloat16(f0.z); hb[3]  = __float2bfloat16(f0.w);
      hb[4]  = __float2bfloat16(f1.x); hb[5]  = __float2bfloat16(f1.y);
      hb[6]  = __float2bfloat16(f1.z); hb[7]  = __float2bfloat16(f1.w);
      hb[8]  = __float2bfloat16(f2.x); hb[9]  = __float2bfloat16(f2.y);
      hb[10] = __float2bfloat16(f2.z); hb[11] = __float2bfloat16(f2.w);
      hb[12] = __float2bfloat16(f3.x); hb[13] = __float2bfloat16(f3.y);
      hb[14] = __float2bfloat16(f3.z); hb[15] = __float2bfloat16(f3.w);
      *(uint4*)&As[ra * AS_LD + sa * 16]     = *(const uint4*)&hb[0];
      *(uint4*)&As[ra * AS_LD + sa * 16 + 8] = *(const uint4*)&hb[8];
      __syncthreads();
      short8 av[4], bv[4];
#pragma unroll
      for (int i = 0; i < 4; ++i) av[i] = *(const short8*)&As[(arow + i * 16) * AS_LD + koff];
#pragma unroll
      for (int j = 0; j < 4; ++j) bv[j] = *(const short8*)&Bs[(brow + j * 16) * 32 + koff];
#pragma unroll
      for (int i = 0; i < 4; ++i)
#pragma unroll
        for (int j = 0; j < 4; ++j)
          acc[i][j] = __builtin_amdgcn_mfma_f32_16x16x32_bf16(av[i], bv[j], acc[i][j], 0, 0, 0);
      __syncthreads();
    }
    const int crow0 = m0 + wr * 64 + (lane >> 4) * 4;
    const int ccol0 = n0 + wc * 64 + (lane & 15);
#pragma unroll
    for (int i = 0; i < 4; ++i)
#pragma unroll
      for (int j = 0; j < 4; ++j)
#pragma unroll
        for (int q = 0; q < 4; ++q)
          C[(size_t)(crow0 + i * 16 + q) * H_DIM + ccol0 + j * 16] = 1.0f + acc[i][j][q];
  } else {
    const int fb = bid - GEMM_BLOCKS;
    size_t i = (size_t)fb * 256 + tid;
    const size_t stride = (size_t)FILLB_BLOCKS * 256;
    const float4 one = make_float4(1.f, 1.f, 1.f, 1.f);
    for (; i < fill_n4; i += stride) fill_p[i] = one;
  }
}

// ---------------------------------------------------------------- launch ----
extern "C" void kernel_launch(void* const* d_in, const int* in_sizes, int n_in,
                              void* d_out, int out_size, void* d_ws, size_t ws_size,
                              hipStream_t stream) {
  const float* x         = (const float*)d_in[0];  // [16][8192][768]
  const float* task_full = (const float*)d_in[1];  // [8][768]
  const float* gate_w    = (const float*)d_in[2];  // [768][16]
  const float* gate_b    = (const float*)d_in[3];  // [16]
  const float* expert_w  = (const float*)d_in[4];  // [16][768][768]
  float* out = (float*)d_out;

  const size_t n_out_main = (size_t)B_BATCH * L_SEQ * H_DIM;  // 100663296
  float* out_tail = out + n_out_main;

  __hip_bfloat16* wct = (__hip_bfloat16*)d_ws;     // 768*768 bf16 = 1.18 MB

  // K_A: inline-gating + wct  |  fill batches 1..8
  const size_t fillA_n4 = (size_t)8 * L_SEQ * H_DIM / 4;
  kA_wct_fill<<<WCT_BLOCKS + FILLA_BLOCKS, 256, 0, stream>>>(
      task_full, gate_w, gate_b, expert_w, wct, out_tail,
      (float4*)(out + (size_t)1 * L_SEQ * H_DIM), fillA_n4);

  // K_B: GEMM (f32 A, fused cvt) -> out[0] with +1.0  |  fill batches 9..15
  const size_t fillB_n4 = (size_t)7 * L_SEQ * H_DIM / 4;
  kB_gemm_fill<<<GEMM_BLOCKS + FILLB_BLOCKS, 256, 0, stream>>>(
      x, wct, out,
      (float4*)(out + (size_t)9 * L_SEQ * H_DIM), fillB_n4);
}